// Round 1
// baseline (3108.621 us; speedup 1.0000x reference)
//
#include <hip/hip_runtime.h>
#include <math.h>

#define HID 64
#define DF  128

__device__ __forceinline__ float silu_f(float v) {
    return v / (1.0f + __expf(-v));
}

// ---------------------------------------------------------------------------
// Transpose weights into [k][f]-major layouts so the unrolled per-lane GEMM
// loops read weights at wave-uniform consecutive addresses (-> s_load_dwordx16).
// Wt1[k*64+f]  = We1[f*257+k]   (k<257, f<64)
// Wt2[k*64+f]  = We2[f*64+k]    (k<64,  f<64)
// Wht1[k*64+f] = Wh1[f*192+k]   (k<192, f<64)
// Wht2[f*128+c]= Wh2[c*64+f]    (f<64,  c<128)
// ---------------------------------------------------------------------------
__global__ void prep_weights(const float* __restrict__ We1, const float* __restrict__ We2,
                             const float* __restrict__ Wh1, const float* __restrict__ Wh2,
                             float* __restrict__ Wt1, float* __restrict__ Wt2,
                             float* __restrict__ Wht1, float* __restrict__ Wht2) {
    int i = blockIdx.x * 256 + threadIdx.x;
    if (i < 257 * 64) {
        int k = i >> 6, f = i & 63;
        Wt1[i] = We1[f * 257 + k];
        return;
    }
    int j = i - 257 * 64;
    if (j < 64 * 64) {
        int k = j >> 6, f = j & 63;
        Wt2[j] = We2[f * 64 + k];
        return;
    }
    j -= 64 * 64;
    if (j < 192 * 64) {
        int k = j >> 6, f = j & 63;
        Wht1[j] = Wh1[f * 192 + k];
        return;
    }
    j -= 192 * 64;
    if (j < 64 * 128) {
        int f = j >> 7, c = j & 127;
        Wht2[j] = Wh2[c * 64 + f];
        return;
    }
}

// ---------------------------------------------------------------------------
// Per-node precompute: Ps[n,f] = sum_k h[n,k]*We1[f,k]
//                      Pd[n,f] = sum_k h[n,k]*We1[f,128+k]
// One node per lane; weights via uniform s_loads; acc in registers.
// ---------------------------------------------------------------------------
__global__ __launch_bounds__(256) void node_pre(const float* __restrict__ h,
                                                const float* __restrict__ Wt1,
                                                float* __restrict__ Ps,
                                                float* __restrict__ Pd, int N) {
    int n = blockIdx.x * 256 + threadIdx.x;
    if (n >= N) return;
    float accS[HID], accD[HID];
#pragma unroll
    for (int f = 0; f < HID; ++f) { accS[f] = 0.f; accD[f] = 0.f; }
    const float4* row = (const float4*)(h + (size_t)n * DF);
    for (int k4 = 0; k4 < DF / 4; ++k4) {
        float4 v = row[k4];
#pragma unroll
        for (int j = 0; j < 4; ++j) {
            float hv = (j == 0) ? v.x : (j == 1) ? v.y : (j == 2) ? v.z : v.w;
            int k = k4 * 4 + j;
#pragma unroll
            for (int f = 0; f < HID; ++f) {
                accS[f] = fmaf(hv, Wt1[k * HID + f], accS[f]);
                accD[f] = fmaf(hv, Wt1[(DF + k) * HID + f], accD[f]);
            }
        }
    }
    float4* ps = (float4*)(Ps + (size_t)n * HID);
    float4* pd = (float4*)(Pd + (size_t)n * HID);
#pragma unroll
    for (int f4 = 0; f4 < HID / 4; ++f4) {
        ps[f4] = make_float4(accS[4 * f4], accS[4 * f4 + 1], accS[4 * f4 + 2], accS[4 * f4 + 3]);
        pd[f4] = make_float4(accD[4 * f4], accD[4 * f4 + 1], accD[4 * f4 + 2], accD[4 * f4 + 3]);
    }
}

// ---------------------------------------------------------------------------
// Edge kernel: one edge per lane.
//   z1 = silu(Ps[src] + Pd[dst] + colW*d_sq + be1)
//   m  = LN(silu(z1 @ We2t + be2)) ; alpha=sigmoid(m.Wg+bg); cw=tanh(alpha*(m.Wx)+bx)
//   atomics: agg_h[dst]+=m*alpha ; agg_x[dst]+=r_n*cw ; deg[dst]+=1
// ---------------------------------------------------------------------------
__global__ __launch_bounds__(256) void edge_kernel(
    const int* __restrict__ src, const int* __restrict__ dst,
    const float* __restrict__ x,
    const float* __restrict__ Ps, const float* __restrict__ Pd,
    const float* __restrict__ Wt1, const float* __restrict__ Wt2,
    const float* __restrict__ be1, const float* __restrict__ be2,
    const float* __restrict__ ln_g, const float* __restrict__ ln_b,
    const float* __restrict__ Wx, const float* __restrict__ bx,
    const float* __restrict__ Wg, const float* __restrict__ bg,
    float* __restrict__ agg_h, float* __restrict__ agg_x, float* __restrict__ deg,
    int E) {
    int e = blockIdx.x * 256 + threadIdx.x;
    if (e >= E) return;
    int s = src[e], d = dst[e];

    float xs0 = x[s * 3], xs1 = x[s * 3 + 1], xs2 = x[s * 3 + 2];
    float xd0 = x[d * 3], xd1 = x[d * 3 + 1], xd2 = x[d * 3 + 2];
    float r0 = xs0 - xd0, r1 = xs1 - xd1, r2 = xs2 - xd2;
    float dsq = r0 * r0 + r1 * r1 + r2 * r2;
    float inv = 1.0f / (sqrtf(dsq) + 1e-8f);
    float rn0 = r0 * inv, rn1 = r1 * inv, rn2 = r2 * inv;

    // layer 1 via precomputed node projections
    float z[HID];
    const float4* ps = (const float4*)(Ps + (size_t)s * HID);
    const float4* pd = (const float4*)(Pd + (size_t)d * HID);
    const float* colW = Wt1 + 256 * HID;  // We1[:,256]
#pragma unroll
    for (int f4 = 0; f4 < HID / 4; ++f4) {
        float4 a = ps[f4];
        float4 b = pd[f4];
        float av[4] = {a.x, a.y, a.z, a.w};
        float bv[4] = {b.x, b.y, b.z, b.w};
#pragma unroll
        for (int j = 0; j < 4; ++j) {
            int f = 4 * f4 + j;
            float v = av[j] + bv[j] + be1[f] + dsq * colW[f];
            z[f] = silu_f(v);
        }
    }

    // layer 2: m = z @ We2t + be2 (fully unrolled, weights via s_load)
    float m[HID];
#pragma unroll
    for (int f = 0; f < HID; ++f) m[f] = be2[f];
#pragma unroll
    for (int k = 0; k < HID; ++k) {
        float zv = z[k];
#pragma unroll
        for (int f = 0; f < HID; ++f) m[f] = fmaf(zv, Wt2[k * HID + f], m[f]);
    }
#pragma unroll
    for (int f = 0; f < HID; ++f) m[f] = silu_f(m[f]);

    // LayerNorm over HID
    float mu = 0.f;
#pragma unroll
    for (int f = 0; f < HID; ++f) mu += m[f];
    mu *= (1.0f / HID);
    float var = 0.f;
#pragma unroll
    for (int f = 0; f < HID; ++f) {
        float t = m[f] - mu;
        var = fmaf(t, t, var);
    }
    var *= (1.0f / HID);
    float rstd = 1.0f / sqrtf(var + 1e-5f);
#pragma unroll
    for (int f = 0; f < HID; ++f) m[f] = (m[f] - mu) * rstd * ln_g[f] + ln_b[f];

    // gates
    float dotg = 0.f, dotx = 0.f;
#pragma unroll
    for (int f = 0; f < HID; ++f) {
        dotg = fmaf(m[f], Wg[f], dotg);
        dotx = fmaf(m[f], Wx[f], dotx);
    }
    float alpha = 1.0f / (1.0f + __expf(-(dotg + bg[0])));
    float ta = __expf(2.0f * fmaf(alpha, dotx, bx[0]));
    float cw = 1.0f - 2.0f / (ta + 1.0f);

    // aggregation (device-scope float atomics)
    float* ah = agg_h + (size_t)d * HID;
#pragma unroll
    for (int f = 0; f < HID; ++f) atomicAdd(&ah[f], m[f] * alpha);
    atomicAdd(&agg_x[d * 3 + 0], rn0 * cw);
    atomicAdd(&agg_x[d * 3 + 1], rn1 * cw);
    atomicAdd(&agg_x[d * 3 + 2], rn2 * cw);
    atomicAdd(&deg[d], 1.0f);
}

// ---------------------------------------------------------------------------
// Node update: hh = silu([h, agg_h] @ Wh1.T + bh1)
//              h_new = h + hh @ Wh2.T + bh2 ; x_new = x + agg_x/max(deg,1)
// ---------------------------------------------------------------------------
__global__ __launch_bounds__(256) void node_kernel(
    const float* __restrict__ h, const float* __restrict__ x,
    const float* __restrict__ agg_h, const float* __restrict__ agg_x,
    const float* __restrict__ deg,
    const float* __restrict__ Wht1, const float* __restrict__ Wht2,
    const float* __restrict__ bh1, const float* __restrict__ bh2,
    float* __restrict__ out, int N) {
    int n = blockIdx.x * 256 + threadIdx.x;
    if (n >= N) return;

    float acc[HID];
#pragma unroll
    for (int f = 0; f < HID; ++f) acc[f] = bh1[f];

    const float4* rowH = (const float4*)(h + (size_t)n * DF);
    for (int k4 = 0; k4 < DF / 4; ++k4) {
        float4 v = rowH[k4];
#pragma unroll
        for (int j = 0; j < 4; ++j) {
            float hv = (j == 0) ? v.x : (j == 1) ? v.y : (j == 2) ? v.z : v.w;
            int k = k4 * 4 + j;
#pragma unroll
            for (int f = 0; f < HID; ++f) acc[f] = fmaf(hv, Wht1[k * HID + f], acc[f]);
        }
    }
    const float4* rowA = (const float4*)(agg_h + (size_t)n * HID);
    for (int k4 = 0; k4 < HID / 4; ++k4) {
        float4 v = rowA[k4];
#pragma unroll
        for (int j = 0; j < 4; ++j) {
            float hv = (j == 0) ? v.x : (j == 1) ? v.y : (j == 2) ? v.z : v.w;
            int k = DF + k4 * 4 + j;
#pragma unroll
            for (int f = 0; f < HID; ++f) acc[f] = fmaf(hv, Wht1[k * HID + f], acc[f]);
        }
    }
#pragma unroll
    for (int f = 0; f < HID; ++f) acc[f] = silu_f(acc[f]);  // hh

    float* oh = out + (size_t)n * DF;
#pragma unroll 1
    for (int p = 0; p < 2; ++p) {
        float o[HID];
#pragma unroll
        for (int c = 0; c < HID; ++c) o[c] = bh2[p * HID + c];
#pragma unroll
        for (int f = 0; f < HID; ++f) {
            float hv = acc[f];
#pragma unroll
            for (int c = 0; c < HID; ++c)
                o[c] = fmaf(hv, Wht2[f * DF + p * HID + c], o[c]);
        }
        const float4* hrow = (const float4*)(h + (size_t)n * DF + p * HID);
        float4* orow = (float4*)(oh + p * HID);
#pragma unroll
        for (int c4 = 0; c4 < HID / 4; ++c4) {
            float4 hv = hrow[c4];
            float4 r;
            r.x = hv.x + o[4 * c4];
            r.y = hv.y + o[4 * c4 + 1];
            r.z = hv.z + o[4 * c4 + 2];
            r.w = hv.w + o[4 * c4 + 3];
            orow[c4] = r;
        }
    }

    float dv = deg[n];
    float invd = 1.0f / fmaxf(dv, 1.0f);
    float* ox = out + (size_t)N * DF + (size_t)n * 3;
    ox[0] = x[n * 3 + 0] + agg_x[n * 3 + 0] * invd;
    ox[1] = x[n * 3 + 1] + agg_x[n * 3 + 1] * invd;
    ox[2] = x[n * 3 + 2] + agg_x[n * 3 + 2] * invd;
}

extern "C" void kernel_launch(void* const* d_in, const int* in_sizes, int n_in,
                              void* d_out, int out_size, void* d_ws, size_t ws_size,
                              hipStream_t stream) {
    const float* h    = (const float*)d_in[0];
    const float* x    = (const float*)d_in[1];
    const int*   ei   = (const int*)d_in[2];
    const float* We1  = (const float*)d_in[3];
    const float* be1  = (const float*)d_in[4];
    const float* We2  = (const float*)d_in[5];
    const float* be2  = (const float*)d_in[6];
    const float* ln_g = (const float*)d_in[7];
    const float* ln_b = (const float*)d_in[8];
    const float* Wh1  = (const float*)d_in[9];
    const float* bh1  = (const float*)d_in[10];
    const float* Wh2  = (const float*)d_in[11];
    const float* bh2  = (const float*)d_in[12];
    const float* Wx   = (const float*)d_in[13];
    const float* bx   = (const float*)d_in[14];
    const float* Wg   = (const float*)d_in[15];
    const float* bg   = (const float*)d_in[16];

    const int E = in_sizes[2] / 2;
    const int N = in_sizes[0] / DF;
    const int* src = ei;
    const int* dst = ei + E;

    float* ws    = (float*)d_ws;
    float* agg_h = ws;                              // N*64
    float* agg_x = agg_h + (size_t)N * HID;         // N*3
    float* dege  = agg_x + (size_t)N * 3;           // N
    float* Wt1   = dege + N;                        // 257*64
    float* Wt2   = Wt1 + 257 * 64;                  // 64*64
    float* Wht1  = Wt2 + 64 * 64;                   // 192*64
    float* Wht2  = Wht1 + 192 * 64;                 // 64*128
    float* tail  = Wht2 + 64 * 128;

    size_t used_floats = (size_t)(tail - ws);
    size_t need_bytes  = (used_floats + (size_t)N * 2 * HID) * sizeof(float);
    float *Ps, *Pd;
    if (ws_size >= need_bytes) {
        Ps = tail;
        Pd = Ps + (size_t)N * HID;
    } else {
        // N*128 floats fit inside d_out (out_size = N*131); d_out is fully
        // overwritten by node_kernel afterwards, so this is safe scratch.
        Ps = (float*)d_out;
        Pd = Ps + (size_t)N * HID;
    }

    // zero the aggregation buffers (agg_h, agg_x, deg are contiguous: N*68)
    hipMemsetAsync(agg_h, 0, (size_t)N * 68 * sizeof(float), stream);

    prep_weights<<<(41024 + 255) / 256, 256, 0, stream>>>(We1, We2, Wh1, Wh2,
                                                          Wt1, Wt2, Wht1, Wht2);
    node_pre<<<(N + 255) / 256, 256, 0, stream>>>(h, Wt1, Ps, Pd, N);
    edge_kernel<<<(E + 255) / 256, 256, 0, stream>>>(src, dst, x, Ps, Pd, Wt1, Wt2,
                                                     be1, be2, ln_g, ln_b, Wx, bx,
                                                     Wg, bg, agg_h, agg_x, dege, E);
    node_kernel<<<(N + 255) / 256, 256, 0, stream>>>(h, x, agg_h, agg_x, dege,
                                                     Wht1, Wht2, bh1, bh2,
                                                     (float*)d_out, N);
}

// Round 2
// 1253.024 us; speedup vs baseline: 2.4809x; 2.4809x over previous
//
#include <hip/hip_runtime.h>
#include <math.h>

#define HID 64
#define DF  128

__device__ __forceinline__ float silu_f(float v) {
    return v / (1.0f + __expf(-v));
}

// ---------------------------------------------------------------------------
// Weight transposes: [k][f]-major so unrolled per-lane loops read weights at
// wave-uniform consecutive addresses (s_load batches).
// ---------------------------------------------------------------------------
__global__ void prep_weights(const float* __restrict__ We1, const float* __restrict__ We2,
                             const float* __restrict__ Wh1, const float* __restrict__ Wh2,
                             float* __restrict__ Wt1, float* __restrict__ Wt2,
                             float* __restrict__ Wht1, float* __restrict__ Wht2) {
    int i = blockIdx.x * 256 + threadIdx.x;
    if (i < 257 * 64) {
        int k = i >> 6, f = i & 63;
        Wt1[i] = We1[f * 257 + k];
        return;
    }
    int j = i - 257 * 64;
    if (j < 64 * 64) {
        int k = j >> 6, f = j & 63;
        Wt2[j] = We2[f * 64 + k];
        return;
    }
    j -= 64 * 64;
    if (j < 192 * 64) {
        int k = j >> 6, f = j & 63;
        Wht1[j] = Wh1[f * 192 + k];
        return;
    }
    j -= 192 * 64;
    if (j < 64 * 128) {
        int f = j >> 7, c = j & 127;
        Wht2[j] = Wh2[c * 64 + f];
        return;
    }
}

// ---------------------------------------------------------------------------
// count: cnt[d] = in-degree; rank[e] = arrival order within d (CSR slot)
// ---------------------------------------------------------------------------
__global__ __launch_bounds__(256) void count_kernel(const int* __restrict__ dst,
                                                    int* __restrict__ cnt,
                                                    int* __restrict__ rank, int E) {
    int e = blockIdx.x * 256 + threadIdx.x;
    if (e >= E) return;
    int r = atomicAdd(&cnt[dst[e]], 1);
    if (rank) rank[e] = r;
}

// exclusive scan of cnt -> off (3 tiny kernels)
__global__ __launch_bounds__(1024) void scan1(const int* __restrict__ cnt,
                                              int* __restrict__ off,
                                              int* __restrict__ bsum, int N) {
    __shared__ int sm[1024];
    int tid = threadIdx.x;
    int i = blockIdx.x * 1024 + tid;
    int v = (i < N) ? cnt[i] : 0;
    sm[tid] = v;
    __syncthreads();
    for (int ofs = 1; ofs < 1024; ofs <<= 1) {
        int t = (tid >= ofs) ? sm[tid - ofs] : 0;
        __syncthreads();
        sm[tid] += t;
        __syncthreads();
    }
    if (i < N) off[i] = sm[tid] - v;       // local exclusive
    if (tid == 1023) bsum[blockIdx.x] = sm[1023];
}

__global__ void scan2(const int* __restrict__ bsum, int* __restrict__ bofs, int Nb) {
    if (threadIdx.x == 0) {
        int s = 0;
        for (int b = 0; b < Nb; ++b) { bofs[b] = s; s += bsum[b]; }
    }
}

__global__ __launch_bounds__(256) void scan3(int* __restrict__ off,
                                             const int* __restrict__ bofs,
                                             int N, int E) {
    int i = blockIdx.x * 256 + threadIdx.x;
    if (i > N) return;
    if (i == N) off[N] = E;
    else off[i] += bofs[i >> 10];
}

// degree-bucket sort of node ids (wave load balance for gather)
__global__ __launch_bounds__(256) void deghist(const int* __restrict__ cnt,
                                               int* __restrict__ dcnt,
                                               int* __restrict__ dnr, int N) {
    int n = blockIdx.x * 256 + threadIdx.x;
    if (n >= N) return;
    int b = min(cnt[n], 63);
    dnr[n] = atomicAdd(&dcnt[b], 1);
}

__global__ void degscan(const int* __restrict__ dcnt, int* __restrict__ dofs) {
    if (threadIdx.x == 0) {
        int s = 0;
        for (int b = 0; b < 64; ++b) { dofs[b] = s; s += dcnt[b]; }
    }
}

__global__ __launch_bounds__(256) void degscatter(const int* __restrict__ cnt,
                                                  const int* __restrict__ dnr,
                                                  const int* __restrict__ dofs,
                                                  int* __restrict__ nodeorder, int N) {
    int n = blockIdx.x * 256 + threadIdx.x;
    if (n >= N) return;
    int b = min(cnt[n], 63);
    nodeorder[dofs[b] + dnr[n]] = n;
}

// eidx[off[dst[e]] + rank[e]] = e
__global__ __launch_bounds__(256) void scatter_edges(const int* __restrict__ dst,
                                                     const int* __restrict__ rank,
                                                     const int* __restrict__ off,
                                                     int* __restrict__ eidx, int E) {
    int e = blockIdx.x * 256 + threadIdx.x;
    if (e >= E) return;
    eidx[off[dst[e]] + rank[e]] = e;
}

// ---------------------------------------------------------------------------
// Per-node precompute of edge-layer-1 projections:
//   Ps[n,f] = sum_k h[n,k]*We1[f,k] ; Pd[n,f] = sum_k h[n,k]*We1[f,128+k]
// ---------------------------------------------------------------------------
__global__ __launch_bounds__(256) void node_pre(const float* __restrict__ h,
                                                const float* __restrict__ Wt1,
                                                float* __restrict__ Ps,
                                                float* __restrict__ Pd, int N) {
    int n = blockIdx.x * 256 + threadIdx.x;
    if (n >= N) return;
    float accS[HID], accD[HID];
#pragma unroll
    for (int f = 0; f < HID; ++f) { accS[f] = 0.f; accD[f] = 0.f; }
    const float4* row = (const float4*)(h + (size_t)n * DF);
    for (int k4 = 0; k4 < DF / 4; ++k4) {
        float4 v = row[k4];
#pragma unroll
        for (int j = 0; j < 4; ++j) {
            float hv = (j == 0) ? v.x : (j == 1) ? v.y : (j == 2) ? v.z : v.w;
            int k = k4 * 4 + j;
#pragma unroll
            for (int f = 0; f < HID; ++f) {
                accS[f] = fmaf(hv, Wt1[k * HID + f], accS[f]);
                accD[f] = fmaf(hv, Wt1[(DF + k) * HID + f], accD[f]);
            }
        }
    }
    float4* ps = (float4*)(Ps + (size_t)n * HID);
    float4* pd = (float4*)(Pd + (size_t)n * HID);
#pragma unroll
    for (int f4 = 0; f4 < HID / 4; ++f4) {
        ps[f4] = make_float4(accS[4 * f4], accS[4 * f4 + 1], accS[4 * f4 + 2], accS[4 * f4 + 3]);
        pd[f4] = make_float4(accD[4 * f4], accD[4 * f4 + 1], accD[4 * f4 + 2], accD[4 * f4 + 3]);
    }
}

// ---------------------------------------------------------------------------
// Gather kernel: one DST NODE per lane. Loops over the node's incoming edges
// (CSR), recomputes the edge MLP inline (weights wave-uniform -> s_loads),
// accumulates agg_h / agg_x in registers. No atomics anywhere.
// ---------------------------------------------------------------------------
__global__ __launch_bounds__(256) void gather_kernel(
    const int* __restrict__ srcI, const int* __restrict__ eidx,
    const int* __restrict__ off, const int* __restrict__ nodeorder,
    const float* __restrict__ x,
    const float* __restrict__ Ps, const float* __restrict__ Pd,
    const float* __restrict__ Wt1, const float* __restrict__ Wt2,
    const float* __restrict__ be1, const float* __restrict__ be2,
    const float* __restrict__ ln_g, const float* __restrict__ ln_b,
    const float* __restrict__ Wx, const float* __restrict__ bx,
    const float* __restrict__ Wg, const float* __restrict__ bg,
    float* __restrict__ agg_h, float* __restrict__ agg_x, int N) {
    int gid = blockIdx.x * 256 + threadIdx.x;
    if (gid >= N) return;
    int n = nodeorder[gid];
    int beg = off[n], end = off[n + 1];

    float xd0 = x[n * 3], xd1 = x[n * 3 + 1], xd2 = x[n * 3 + 2];

    // hoist Pd[n] + be1 (this node is dst for all its edges)
    float base[HID];
    {
        const float4* pd = (const float4*)(Pd + (size_t)n * HID);
#pragma unroll
        for (int f4 = 0; f4 < HID / 4; ++f4) {
            float4 b = pd[f4];
            base[4 * f4 + 0] = b.x + be1[4 * f4 + 0];
            base[4 * f4 + 1] = b.y + be1[4 * f4 + 1];
            base[4 * f4 + 2] = b.z + be1[4 * f4 + 2];
            base[4 * f4 + 3] = b.w + be1[4 * f4 + 3];
        }
    }

    float acc[HID];
#pragma unroll
    for (int f = 0; f < HID; ++f) acc[f] = 0.f;
    float ax0 = 0.f, ax1 = 0.f, ax2 = 0.f;

    const float* colW = Wt1 + 256 * HID;  // We1[:,256] (d_sq column)

    for (int i = beg; i < end; ++i) {
        int e = eidx[i];
        int s = srcI[e];
        float r0 = x[s * 3] - xd0, r1 = x[s * 3 + 1] - xd1, r2 = x[s * 3 + 2] - xd2;
        float dsq = r0 * r0 + r1 * r1 + r2 * r2;
        float inv = 1.0f / (sqrtf(dsq) + 1e-8f);
        float rn0 = r0 * inv, rn1 = r1 * inv, rn2 = r2 * inv;

        // layer-2 accumulators (init with bias); z_k consumed on the fly
        float m[HID];
#pragma unroll
        for (int f = 0; f < HID; ++f) m[f] = be2[f];

        const float4* ps = (const float4*)(Ps + (size_t)s * HID);
#pragma unroll
        for (int k4 = 0; k4 < HID / 4; ++k4) {
            float4 v = ps[k4];
            float pv[4] = {v.x, v.y, v.z, v.w};
#pragma unroll
            for (int j = 0; j < 4; ++j) {
                int k = 4 * k4 + j;
                float zk = silu_f(pv[j] + base[k] + dsq * colW[k]);
#pragma unroll
                for (int f = 0; f < HID; ++f) m[f] = fmaf(zk, Wt2[k * HID + f], m[f]);
            }
        }
#pragma unroll
        for (int f = 0; f < HID; ++f) m[f] = silu_f(m[f]);

        // LayerNorm
        float mu = 0.f;
#pragma unroll
        for (int f = 0; f < HID; ++f) mu += m[f];
        mu *= (1.0f / HID);
        float var = 0.f;
#pragma unroll
        for (int f = 0; f < HID; ++f) {
            float t = m[f] - mu;
            var = fmaf(t, t, var);
        }
        var *= (1.0f / HID);
        float rstd = 1.0f / sqrtf(var + 1e-5f);
#pragma unroll
        for (int f = 0; f < HID; ++f) m[f] = (m[f] - mu) * rstd * ln_g[f] + ln_b[f];

        // gates
        float dotg = 0.f, dotx = 0.f;
#pragma unroll
        for (int f = 0; f < HID; ++f) {
            dotg = fmaf(m[f], Wg[f], dotg);
            dotx = fmaf(m[f], Wx[f], dotx);
        }
        float alpha = 1.0f / (1.0f + __expf(-(dotg + bg[0])));
        float ta = __expf(2.0f * fmaf(alpha, dotx, bx[0]));
        float cw = 1.0f - 2.0f / (ta + 1.0f);

#pragma unroll
        for (int f = 0; f < HID; ++f) acc[f] = fmaf(m[f], alpha, acc[f]);
        ax0 = fmaf(rn0, cw, ax0);
        ax1 = fmaf(rn1, cw, ax1);
        ax2 = fmaf(rn2, cw, ax2);
    }

    float4* ah = (float4*)(agg_h + (size_t)n * HID);
#pragma unroll
    for (int f4 = 0; f4 < HID / 4; ++f4)
        ah[f4] = make_float4(acc[4 * f4], acc[4 * f4 + 1], acc[4 * f4 + 2], acc[4 * f4 + 3]);
    agg_x[n * 3 + 0] = ax0;
    agg_x[n * 3 + 1] = ax1;
    agg_x[n * 3 + 2] = ax2;
}

// ---------------------------------------------------------------------------
// Fallback edge kernel (atomic aggregation) — used only if ws is too small
// for the CSR path. Identical math to round 1 (deg now via count_kernel).
// ---------------------------------------------------------------------------
__global__ __launch_bounds__(256) void edge_kernel_atomic(
    const int* __restrict__ src, const int* __restrict__ dst,
    const float* __restrict__ x,
    const float* __restrict__ Ps, const float* __restrict__ Pd,
    const float* __restrict__ Wt1, const float* __restrict__ Wt2,
    const float* __restrict__ be1, const float* __restrict__ be2,
    const float* __restrict__ ln_g, const float* __restrict__ ln_b,
    const float* __restrict__ Wx, const float* __restrict__ bx,
    const float* __restrict__ Wg, const float* __restrict__ bg,
    float* __restrict__ agg_h, float* __restrict__ agg_x, int E) {
    int e = blockIdx.x * 256 + threadIdx.x;
    if (e >= E) return;
    int s = src[e], d = dst[e];
    float r0 = x[s * 3] - x[d * 3], r1 = x[s * 3 + 1] - x[d * 3 + 1], r2 = x[s * 3 + 2] - x[d * 3 + 2];
    float dsq = r0 * r0 + r1 * r1 + r2 * r2;
    float inv = 1.0f / (sqrtf(dsq) + 1e-8f);
    float rn0 = r0 * inv, rn1 = r1 * inv, rn2 = r2 * inv;
    float z[HID];
    const float4* ps = (const float4*)(Ps + (size_t)s * HID);
    const float4* pd = (const float4*)(Pd + (size_t)d * HID);
    const float* colW = Wt1 + 256 * HID;
#pragma unroll
    for (int f4 = 0; f4 < HID / 4; ++f4) {
        float4 a = ps[f4];
        float4 b = pd[f4];
        float av[4] = {a.x, a.y, a.z, a.w};
        float bv[4] = {b.x, b.y, b.z, b.w};
#pragma unroll
        for (int j = 0; j < 4; ++j) {
            int f = 4 * f4 + j;
            z[f] = silu_f(av[j] + bv[j] + be1[f] + dsq * colW[f]);
        }
    }
    float m[HID];
#pragma unroll
    for (int f = 0; f < HID; ++f) m[f] = be2[f];
#pragma unroll
    for (int k = 0; k < HID; ++k) {
        float zv = z[k];
#pragma unroll
        for (int f = 0; f < HID; ++f) m[f] = fmaf(zv, Wt2[k * HID + f], m[f]);
    }
#pragma unroll
    for (int f = 0; f < HID; ++f) m[f] = silu_f(m[f]);
    float mu = 0.f;
#pragma unroll
    for (int f = 0; f < HID; ++f) mu += m[f];
    mu *= (1.0f / HID);
    float var = 0.f;
#pragma unroll
    for (int f = 0; f < HID; ++f) {
        float t = m[f] - mu;
        var = fmaf(t, t, var);
    }
    var *= (1.0f / HID);
    float rstd = 1.0f / sqrtf(var + 1e-5f);
#pragma unroll
    for (int f = 0; f < HID; ++f) m[f] = (m[f] - mu) * rstd * ln_g[f] + ln_b[f];
    float dotg = 0.f, dotx = 0.f;
#pragma unroll
    for (int f = 0; f < HID; ++f) {
        dotg = fmaf(m[f], Wg[f], dotg);
        dotx = fmaf(m[f], Wx[f], dotx);
    }
    float alpha = 1.0f / (1.0f + __expf(-(dotg + bg[0])));
    float ta = __expf(2.0f * fmaf(alpha, dotx, bx[0]));
    float cw = 1.0f - 2.0f / (ta + 1.0f);
    float* ah = agg_h + (size_t)d * HID;
#pragma unroll
    for (int f = 0; f < HID; ++f) atomicAdd(&ah[f], m[f] * alpha);
    atomicAdd(&agg_x[d * 3 + 0], rn0 * cw);
    atomicAdd(&agg_x[d * 3 + 1], rn1 * cw);
    atomicAdd(&agg_x[d * 3 + 2], rn2 * cw);
}

// ---------------------------------------------------------------------------
// Node update: hh = silu([h, agg_h] @ Wh1.T + bh1)
//              h_new = h + hh @ Wh2.T + bh2 ; x_new = x + agg_x/max(deg,1)
// ---------------------------------------------------------------------------
__global__ __launch_bounds__(256) void node_kernel(
    const float* __restrict__ h, const float* __restrict__ x,
    const float* __restrict__ agg_h, const float* __restrict__ agg_x,
    const int* __restrict__ degI,
    const float* __restrict__ Wht1, const float* __restrict__ Wht2,
    const float* __restrict__ bh1, const float* __restrict__ bh2,
    float* __restrict__ out, int N) {
    int n = blockIdx.x * 256 + threadIdx.x;
    if (n >= N) return;

    float acc[HID];
#pragma unroll
    for (int f = 0; f < HID; ++f) acc[f] = bh1[f];

    const float4* rowH = (const float4*)(h + (size_t)n * DF);
    for (int k4 = 0; k4 < DF / 4; ++k4) {
        float4 v = rowH[k4];
#pragma unroll
        for (int j = 0; j < 4; ++j) {
            float hv = (j == 0) ? v.x : (j == 1) ? v.y : (j == 2) ? v.z : v.w;
            int k = k4 * 4 + j;
#pragma unroll
            for (int f = 0; f < HID; ++f) acc[f] = fmaf(hv, Wht1[k * HID + f], acc[f]);
        }
    }
    const float4* rowA = (const float4*)(agg_h + (size_t)n * HID);
    for (int k4 = 0; k4 < HID / 4; ++k4) {
        float4 v = rowA[k4];
#pragma unroll
        for (int j = 0; j < 4; ++j) {
            float hv = (j == 0) ? v.x : (j == 1) ? v.y : (j == 2) ? v.z : v.w;
            int k = DF + k4 * 4 + j;
#pragma unroll
            for (int f = 0; f < HID; ++f) acc[f] = fmaf(hv, Wht1[k * HID + f], acc[f]);
        }
    }
#pragma unroll
    for (int f = 0; f < HID; ++f) acc[f] = silu_f(acc[f]);  // hh

    float* oh = out + (size_t)n * DF;
#pragma unroll 1
    for (int p = 0; p < 2; ++p) {
        float o[HID];
#pragma unroll
        for (int c = 0; c < HID; ++c) o[c] = bh2[p * HID + c];
#pragma unroll
        for (int f = 0; f < HID; ++f) {
            float hv = acc[f];
#pragma unroll
            for (int c = 0; c < HID; ++c)
                o[c] = fmaf(hv, Wht2[f * DF + p * HID + c], o[c]);
        }
        const float4* hrow = (const float4*)(h + (size_t)n * DF + p * HID);
        float4* orow = (float4*)(oh + p * HID);
#pragma unroll
        for (int c4 = 0; c4 < HID / 4; ++c4) {
            float4 hv = hrow[c4];
            float4 r;
            r.x = hv.x + o[4 * c4];
            r.y = hv.y + o[4 * c4 + 1];
            r.z = hv.z + o[4 * c4 + 2];
            r.w = hv.w + o[4 * c4 + 3];
            orow[c4] = r;
        }
    }

    float dv = (float)degI[n];
    float invd = 1.0f / fmaxf(dv, 1.0f);
    float* ox = out + (size_t)N * DF + (size_t)n * 3;
    ox[0] = x[n * 3 + 0] + agg_x[n * 3 + 0] * invd;
    ox[1] = x[n * 3 + 1] + agg_x[n * 3 + 1] * invd;
    ox[2] = x[n * 3 + 2] + agg_x[n * 3 + 2] * invd;
}

extern "C" void kernel_launch(void* const* d_in, const int* in_sizes, int n_in,
                              void* d_out, int out_size, void* d_ws, size_t ws_size,
                              hipStream_t stream) {
    const float* h    = (const float*)d_in[0];
    const float* x    = (const float*)d_in[1];
    const int*   ei   = (const int*)d_in[2];
    const float* We1  = (const float*)d_in[3];
    const float* be1  = (const float*)d_in[4];
    const float* We2  = (const float*)d_in[5];
    const float* be2  = (const float*)d_in[6];
    const float* ln_g = (const float*)d_in[7];
    const float* ln_b = (const float*)d_in[8];
    const float* Wh1  = (const float*)d_in[9];
    const float* bh1  = (const float*)d_in[10];
    const float* Wh2  = (const float*)d_in[11];
    const float* bh2  = (const float*)d_in[12];
    const float* Wx   = (const float*)d_in[13];
    const float* bx   = (const float*)d_in[14];
    const float* Wg   = (const float*)d_in[15];
    const float* bg   = (const float*)d_in[16];

    const int E = in_sizes[2] / 2;
    const int N = in_sizes[0] / DF;
    const int* src = ei;
    const int* dst = ei + E;

    // ---- workspace carve (16B aligned regions) ----
    char* base = (char*)d_ws;
    size_t o = 0;
    auto carve = [&](size_t bytes) -> void* {
        void* r = base + o;
        o = (o + bytes + 15) & ~(size_t)15;
        return r;
    };
    float* agg_h = (float*)carve((size_t)N * HID * 4);
    float* agg_x = (float*)carve((size_t)N * 3 * 4);
    float* Wt1   = (float*)carve(257 * 64 * 4);
    float* Wt2   = (float*)carve(64 * 64 * 4);
    float* Wht1  = (float*)carve(192 * 64 * 4);
    float* Wht2  = (float*)carve(64 * 128 * 4);
    int*   cnt   = (int*)carve((size_t)N * 4);
    size_t need_fallback = o;
    int*   off   = (int*)carve(((size_t)N + 1) * 4);
    int*   bsum  = (int*)carve(256 * 4);
    int*   bofs  = (int*)carve(256 * 4);
    int*   dcnt  = (int*)carve(64 * 4);
    int*   dofs  = (int*)carve(64 * 4);
    int*   dnr   = (int*)carve((size_t)N * 4);
    int*   nodeorder = (int*)carve((size_t)N * 4);
    int*   rank  = (int*)carve((size_t)E * 4);
    int*   eidx  = (int*)carve((size_t)E * 4);
    size_t need_full = o;

    // Ps/Pd live in d_out (N*128 <= out_size N*131); d_out is fully
    // overwritten by node_kernel afterwards.
    float* Ps = (float*)d_out;
    float* Pd = Ps + (size_t)N * HID;

    const int gN  = (N + 255) / 256;
    const int gE  = (E + 255) / 256;
    const int Nb  = (N + 1023) / 1024;

    hipMemsetAsync(cnt, 0, (size_t)N * 4, stream);
    prep_weights<<<(41024 + 255) / 256, 256, 0, stream>>>(We1, We2, Wh1, Wh2,
                                                          Wt1, Wt2, Wht1, Wht2);
    node_pre<<<gN, 256, 0, stream>>>(h, Wt1, Ps, Pd, N);

    if (ws_size >= need_full) {
        // ---- CSR build ----
        hipMemsetAsync(dcnt, 0, 64 * 4, stream);
        count_kernel<<<gE, 256, 0, stream>>>(dst, cnt, rank, E);
        scan1<<<Nb, 1024, 0, stream>>>(cnt, off, bsum, N);
        scan2<<<1, 64, 0, stream>>>(bsum, bofs, Nb);
        scan3<<<(N + 256) / 256, 256, 0, stream>>>(off, bofs, N, E);
        scatter_edges<<<gE, 256, 0, stream>>>(dst, rank, off, eidx, E);
        // degree-sorted node order (wave load balance)
        deghist<<<gN, 256, 0, stream>>>(cnt, dcnt, dnr, N);
        degscan<<<1, 64, 0, stream>>>(dcnt, dofs);
        degscatter<<<gN, 256, 0, stream>>>(cnt, dnr, dofs, nodeorder, N);
        // ---- fused gather (no atomics) ----
        gather_kernel<<<gN, 256, 0, stream>>>(src, eidx, off, nodeorder, x, Ps, Pd,
                                              Wt1, Wt2, be1, be2, ln_g, ln_b,
                                              Wx, bx, Wg, bg, agg_h, agg_x, N);
    } else {
        // ---- fallback: atomic aggregation (round-1 path) ----
        hipMemsetAsync(agg_h, 0, (size_t)N * 67 * 4, stream);
        count_kernel<<<gE, 256, 0, stream>>>(dst, cnt, nullptr, E);
        edge_kernel_atomic<<<gE, 256, 0, stream>>>(src, dst, x, Ps, Pd, Wt1, Wt2,
                                                   be1, be2, ln_g, ln_b, Wx, bx,
                                                   Wg, bg, agg_h, agg_x, E);
    }

    node_kernel<<<gN, 256, 0, stream>>>(h, x, agg_h, agg_x, cnt,
                                        Wht1, Wht2, bh1, bh2, (float*)d_out, N);
}

// Round 3
// 900.664 us; speedup vs baseline: 3.4515x; 1.3912x over previous
//
#include <hip/hip_runtime.h>
#include <math.h>

#define HID 64
#define DF  128
#define GS  8   // edge-slice lanes per node in gather

__device__ __forceinline__ float silu_f(float v) {
    return v / (1.0f + __expf(-v));
}

// ---------------------------------------------------------------------------
// Weight transposes: [k][f]-major so unrolled per-lane loops read weights at
// wave-uniform consecutive addresses (s_load batches).
// ---------------------------------------------------------------------------
__global__ void prep_weights(const float* __restrict__ We1, const float* __restrict__ We2,
                             const float* __restrict__ Wh1, const float* __restrict__ Wh2,
                             float* __restrict__ Wt1, float* __restrict__ Wt2,
                             float* __restrict__ Wht1, float* __restrict__ Wht2) {
    int i = blockIdx.x * 256 + threadIdx.x;
    if (i < 257 * 64) {
        int k = i >> 6, f = i & 63;
        Wt1[i] = We1[f * 257 + k];
        return;
    }
    int j = i - 257 * 64;
    if (j < 64 * 64) {
        int k = j >> 6, f = j & 63;
        Wt2[j] = We2[f * 64 + k];
        return;
    }
    j -= 64 * 64;
    if (j < 192 * 64) {
        int k = j >> 6, f = j & 63;
        Wht1[j] = Wh1[f * 192 + k];
        return;
    }
    j -= 192 * 64;
    if (j < 64 * 128) {
        int f = j >> 7, c = j & 127;
        Wht2[j] = Wh2[c * 64 + f];
        return;
    }
}

// ---------------------------------------------------------------------------
// CSR build
// ---------------------------------------------------------------------------
__global__ __launch_bounds__(256) void count_kernel(const int* __restrict__ dst,
                                                    int* __restrict__ cnt,
                                                    int* __restrict__ rank, int E) {
    int e = blockIdx.x * 256 + threadIdx.x;
    if (e >= E) return;
    int r = atomicAdd(&cnt[dst[e]], 1);
    if (rank) rank[e] = r;
}

__global__ __launch_bounds__(1024) void scan1(const int* __restrict__ cnt,
                                              int* __restrict__ off,
                                              int* __restrict__ bsum, int N) {
    __shared__ int sm[1024];
    int tid = threadIdx.x;
    int i = blockIdx.x * 1024 + tid;
    int v = (i < N) ? cnt[i] : 0;
    sm[tid] = v;
    __syncthreads();
    for (int ofs = 1; ofs < 1024; ofs <<= 1) {
        int t = (tid >= ofs) ? sm[tid - ofs] : 0;
        __syncthreads();
        sm[tid] += t;
        __syncthreads();
    }
    if (i < N) off[i] = sm[tid] - v;
    if (tid == 1023) bsum[blockIdx.x] = sm[1023];
}

__global__ void scan2(const int* __restrict__ bsum, int* __restrict__ bofs, int Nb) {
    if (threadIdx.x == 0) {
        int s = 0;
        for (int b = 0; b < Nb; ++b) { bofs[b] = s; s += bsum[b]; }
    }
}

__global__ __launch_bounds__(256) void scan3(int* __restrict__ off,
                                             const int* __restrict__ bofs,
                                             int N, int E) {
    int i = blockIdx.x * 256 + threadIdx.x;
    if (i > N) return;
    if (i == N) off[N] = E;
    else off[i] += bofs[i >> 10];
}

__global__ __launch_bounds__(256) void deghist(const int* __restrict__ cnt,
                                               int* __restrict__ dcnt,
                                               int* __restrict__ dnr, int N) {
    int n = blockIdx.x * 256 + threadIdx.x;
    if (n >= N) return;
    int b = min(cnt[n], 63);
    dnr[n] = atomicAdd(&dcnt[b], 1);
}

__global__ void degscan(const int* __restrict__ dcnt, int* __restrict__ dofs) {
    if (threadIdx.x == 0) {
        int s = 0;
        for (int b = 0; b < 64; ++b) { dofs[b] = s; s += dcnt[b]; }
    }
}

__global__ __launch_bounds__(256) void degscatter(const int* __restrict__ cnt,
                                                  const int* __restrict__ dnr,
                                                  const int* __restrict__ dofs,
                                                  int* __restrict__ nodeorder, int N) {
    int n = blockIdx.x * 256 + threadIdx.x;
    if (n >= N) return;
    int b = min(cnt[n], 63);
    nodeorder[dofs[b] + dnr[n]] = n;
}

// csr_src[off[dst[e]] + rank[e]] = src[e]   (stores src id directly: one less
// dependent load in the gather inner loop)
__global__ __launch_bounds__(256) void scatter_src(const int* __restrict__ dst,
                                                   const int* __restrict__ srcI,
                                                   const int* __restrict__ rank,
                                                   const int* __restrict__ off,
                                                   int* __restrict__ csr_src, int E) {
    int e = blockIdx.x * 256 + threadIdx.x;
    if (e >= E) return;
    csr_src[off[dst[e]] + rank[e]] = srcI[e];
}

// ---------------------------------------------------------------------------
// node_pre (wave-feature-split): block = 256 threads = 4 waves over 64 nodes.
// Wave w computes features [16w,16w+16) of Ps and Pd. Weight addresses are
// wave-uniform (readfirstlane on the wave id) -> s_load path.
// ---------------------------------------------------------------------------
__global__ __launch_bounds__(256) void node_pre(const float* __restrict__ h,
                                                const float* __restrict__ Wt1,
                                                float* __restrict__ Ps,
                                                float* __restrict__ Pd, int N) {
    int lane = threadIdx.x & 63;
    int w = __builtin_amdgcn_readfirstlane(threadIdx.x >> 6);
    int n = blockIdx.x * 64 + lane;
    if (n >= N) return;
    int f0 = w * 16;
    float accS[16], accD[16];
#pragma unroll
    for (int j = 0; j < 16; ++j) { accS[j] = 0.f; accD[j] = 0.f; }
    const float4* row = (const float4*)(h + (size_t)n * DF);
    for (int k4 = 0; k4 < DF / 4; ++k4) {
        float4 v = row[k4];
        float hv4[4] = {v.x, v.y, v.z, v.w};
#pragma unroll
        for (int jj = 0; jj < 4; ++jj) {
            int k = k4 * 4 + jj;
            float hv = hv4[jj];
#pragma unroll
            for (int j = 0; j < 16; ++j) {
                accS[j] = fmaf(hv, Wt1[k * HID + f0 + j], accS[j]);
                accD[j] = fmaf(hv, Wt1[(DF + k) * HID + f0 + j], accD[j]);
            }
        }
    }
    float4* ps = (float4*)(Ps + (size_t)n * HID + f0);
    float4* pd = (float4*)(Pd + (size_t)n * HID + f0);
#pragma unroll
    for (int j4 = 0; j4 < 4; ++j4) {
        ps[j4] = make_float4(accS[4 * j4], accS[4 * j4 + 1], accS[4 * j4 + 2], accS[4 * j4 + 3]);
        pd[j4] = make_float4(accD[4 * j4], accD[4 * j4 + 1], accD[4 * j4 + 2], accD[4 * j4 + 3]);
    }
}

// ---------------------------------------------------------------------------
// Gather: GS=8 lanes per dst node, each lane takes every-GS'th incoming edge,
// recomputes the edge MLP inline, then an 8-lane shfl_xor tree combines the
// partial aggregates. launch_bounds(256,2): 256-VGPR budget -> no spills.
// ---------------------------------------------------------------------------
__global__ __launch_bounds__(256, 2) void gather_kernel(
    const int* __restrict__ csr_src, const int* __restrict__ off,
    const int* __restrict__ nodeorder, const float* __restrict__ x,
    const float* __restrict__ Ps, const float* __restrict__ Pd,
    const float* __restrict__ Wt1, const float* __restrict__ Wt2,
    const float* __restrict__ be1, const float* __restrict__ be2,
    const float* __restrict__ ln_g, const float* __restrict__ ln_b,
    const float* __restrict__ Wx, const float* __restrict__ bx,
    const float* __restrict__ Wg, const float* __restrict__ bg,
    float* __restrict__ agg_h, float* __restrict__ agg_x, int N) {
    int gid = blockIdx.x * 256 + threadIdx.x;
    int slot = gid >> 3, sub = gid & (GS - 1);
    if (slot >= N) return;
    int n = nodeorder[slot];
    int beg = off[n], end = off[n + 1];

    float xd0 = x[n * 3], xd1 = x[n * 3 + 1], xd2 = x[n * 3 + 2];
    const float* colW = Wt1 + 256 * HID;  // We1[:,256] (d_sq column)
    const float4* pd = (const float4*)(Pd + (size_t)n * HID);

    float acc[HID];
#pragma unroll
    for (int f = 0; f < HID; ++f) acc[f] = 0.f;
    float ax0 = 0.f, ax1 = 0.f, ax2 = 0.f;

    for (int i = beg + sub; i < end; i += GS) {
        int s = csr_src[i];
        float r0 = x[s * 3] - xd0, r1 = x[s * 3 + 1] - xd1, r2 = x[s * 3 + 2] - xd2;
        float dsq = r0 * r0 + r1 * r1 + r2 * r2;
        float inv = 1.0f / (sqrtf(dsq) + 1e-8f);
        float rn0 = r0 * inv, rn1 = r1 * inv, rn2 = r2 * inv;

        float m[HID];
#pragma unroll
        for (int f = 0; f < HID; ++f) m[f] = be2[f];

        const float4* ps = (const float4*)(Ps + (size_t)s * HID);
#pragma unroll
        for (int k4 = 0; k4 < HID / 4; ++k4) {
            float4 a = ps[k4];
            float4 b = pd[k4];
            float av[4] = {a.x, a.y, a.z, a.w};
            float bv[4] = {b.x, b.y, b.z, b.w};
#pragma unroll
            for (int j = 0; j < 4; ++j) {
                int k = 4 * k4 + j;
                float zk = silu_f(av[j] + bv[j] + be1[k] + dsq * colW[k]);
#pragma unroll
                for (int f = 0; f < HID; ++f) m[f] = fmaf(zk, Wt2[k * HID + f], m[f]);
            }
        }
#pragma unroll
        for (int f = 0; f < HID; ++f) m[f] = silu_f(m[f]);

        // LayerNorm
        float mu = 0.f;
#pragma unroll
        for (int f = 0; f < HID; ++f) mu += m[f];
        mu *= (1.0f / HID);
        float var = 0.f;
#pragma unroll
        for (int f = 0; f < HID; ++f) {
            float t = m[f] - mu;
            var = fmaf(t, t, var);
        }
        var *= (1.0f / HID);
        float rstd = 1.0f / sqrtf(var + 1e-5f);
#pragma unroll
        for (int f = 0; f < HID; ++f) m[f] = (m[f] - mu) * rstd * ln_g[f] + ln_b[f];

        // gates
        float dotg = 0.f, dotx = 0.f;
#pragma unroll
        for (int f = 0; f < HID; ++f) {
            dotg = fmaf(m[f], Wg[f], dotg);
            dotx = fmaf(m[f], Wx[f], dotx);
        }
        float alpha = 1.0f / (1.0f + __expf(-(dotg + bg[0])));
        float ta = __expf(2.0f * fmaf(alpha, dotx, bx[0]));
        float cw = 1.0f - 2.0f / (ta + 1.0f);

#pragma unroll
        for (int f = 0; f < HID; ++f) acc[f] = fmaf(m[f], alpha, acc[f]);
        ax0 = fmaf(rn0, cw, ax0);
        ax1 = fmaf(rn1, cw, ax1);
        ax2 = fmaf(rn2, cw, ax2);
    }

    // combine the GS partial aggregates (8-lane groups are wave-aligned)
#pragma unroll
    for (int d = 1; d < GS; d <<= 1) {
#pragma unroll
        for (int f = 0; f < HID; ++f) acc[f] += __shfl_xor(acc[f], d, 64);
        ax0 += __shfl_xor(ax0, d, 64);
        ax1 += __shfl_xor(ax1, d, 64);
        ax2 += __shfl_xor(ax2, d, 64);
    }

    if (sub == 0) {
        float4* ah = (float4*)(agg_h + (size_t)n * HID);
#pragma unroll
        for (int f4 = 0; f4 < HID / 4; ++f4)
            ah[f4] = make_float4(acc[4 * f4], acc[4 * f4 + 1], acc[4 * f4 + 2], acc[4 * f4 + 3]);
        agg_x[n * 3 + 0] = ax0;
        agg_x[n * 3 + 1] = ax1;
        agg_x[n * 3 + 2] = ax2;
    }
}

// ---------------------------------------------------------------------------
// Fallback edge kernel (atomic aggregation) — only if ws too small for CSR.
// ---------------------------------------------------------------------------
__global__ __launch_bounds__(256) void edge_kernel_atomic(
    const int* __restrict__ src, const int* __restrict__ dst,
    const float* __restrict__ x,
    const float* __restrict__ Ps, const float* __restrict__ Pd,
    const float* __restrict__ Wt1, const float* __restrict__ Wt2,
    const float* __restrict__ be1, const float* __restrict__ be2,
    const float* __restrict__ ln_g, const float* __restrict__ ln_b,
    const float* __restrict__ Wx, const float* __restrict__ bx,
    const float* __restrict__ Wg, const float* __restrict__ bg,
    float* __restrict__ agg_h, float* __restrict__ agg_x, int E) {
    int e = blockIdx.x * 256 + threadIdx.x;
    if (e >= E) return;
    int s = src[e], d = dst[e];
    float r0 = x[s * 3] - x[d * 3], r1 = x[s * 3 + 1] - x[d * 3 + 1], r2 = x[s * 3 + 2] - x[d * 3 + 2];
    float dsq = r0 * r0 + r1 * r1 + r2 * r2;
    float inv = 1.0f / (sqrtf(dsq) + 1e-8f);
    float rn0 = r0 * inv, rn1 = r1 * inv, rn2 = r2 * inv;
    float z[HID];
    const float4* ps = (const float4*)(Ps + (size_t)s * HID);
    const float4* pd = (const float4*)(Pd + (size_t)d * HID);
    const float* colW = Wt1 + 256 * HID;
#pragma unroll
    for (int f4 = 0; f4 < HID / 4; ++f4) {
        float4 a = ps[f4];
        float4 b = pd[f4];
        float av[4] = {a.x, a.y, a.z, a.w};
        float bv[4] = {b.x, b.y, b.z, b.w};
#pragma unroll
        for (int j = 0; j < 4; ++j) {
            int f = 4 * f4 + j;
            z[f] = silu_f(av[j] + bv[j] + be1[f] + dsq * colW[f]);
        }
    }
    float m[HID];
#pragma unroll
    for (int f = 0; f < HID; ++f) m[f] = be2[f];
#pragma unroll
    for (int k = 0; k < HID; ++k) {
        float zv = z[k];
#pragma unroll
        for (int f = 0; f < HID; ++f) m[f] = fmaf(zv, Wt2[k * HID + f], m[f]);
    }
#pragma unroll
    for (int f = 0; f < HID; ++f) m[f] = silu_f(m[f]);
    float mu = 0.f;
#pragma unroll
    for (int f = 0; f < HID; ++f) mu += m[f];
    mu *= (1.0f / HID);
    float var = 0.f;
#pragma unroll
    for (int f = 0; f < HID; ++f) {
        float t = m[f] - mu;
        var = fmaf(t, t, var);
    }
    var *= (1.0f / HID);
    float rstd = 1.0f / sqrtf(var + 1e-5f);
#pragma unroll
    for (int f = 0; f < HID; ++f) m[f] = (m[f] - mu) * rstd * ln_g[f] + ln_b[f];
    float dotg = 0.f, dotx = 0.f;
#pragma unroll
    for (int f = 0; f < HID; ++f) {
        dotg = fmaf(m[f], Wg[f], dotg);
        dotx = fmaf(m[f], Wx[f], dotx);
    }
    float alpha = 1.0f / (1.0f + __expf(-(dotg + bg[0])));
    float ta = __expf(2.0f * fmaf(alpha, dotx, bx[0]));
    float cw = 1.0f - 2.0f / (ta + 1.0f);
    float* ah = agg_h + (size_t)d * HID;
#pragma unroll
    for (int f = 0; f < HID; ++f) atomicAdd(&ah[f], m[f] * alpha);
    atomicAdd(&agg_x[d * 3 + 0], rn0 * cw);
    atomicAdd(&agg_x[d * 3 + 1], rn1 * cw);
    atomicAdd(&agg_x[d * 3 + 2], rn2 * cw);
}

// ---------------------------------------------------------------------------
// node_kernel (wave-feature-split): block = 256 threads = 4 waves over 64
// nodes. Phase 1: wave w computes hh[16-feature strip] -> LDS (stride 65,
// conflict-free). Phase 2: wave w computes 32 output cols from the full hh
// row; wave 0 also writes x_out.
// ---------------------------------------------------------------------------
__global__ __launch_bounds__(256) void node_kernel(
    const float* __restrict__ h, const float* __restrict__ x,
    const float* __restrict__ agg_h, const float* __restrict__ agg_x,
    const int* __restrict__ degI,
    const float* __restrict__ Wht1, const float* __restrict__ Wht2,
    const float* __restrict__ bh1, const float* __restrict__ bh2,
    float* __restrict__ out, int N) {
    __shared__ float hh[64 * 65];
    int lane = threadIdx.x & 63;
    int w = __builtin_amdgcn_readfirstlane(threadIdx.x >> 6);
    int n = blockIdx.x * 64 + lane;

    if (n < N) {
        int f0 = w * 16;
        float t[16];
#pragma unroll
        for (int j = 0; j < 16; ++j) t[j] = bh1[f0 + j];
        const float4* rowH = (const float4*)(h + (size_t)n * DF);
        for (int k4 = 0; k4 < DF / 4; ++k4) {
            float4 v = rowH[k4];
            float hv4[4] = {v.x, v.y, v.z, v.w};
#pragma unroll
            for (int jj = 0; jj < 4; ++jj) {
                int k = k4 * 4 + jj;
                float hv = hv4[jj];
#pragma unroll
                for (int j = 0; j < 16; ++j) t[j] = fmaf(hv, Wht1[k * HID + f0 + j], t[j]);
            }
        }
        const float4* rowA = (const float4*)(agg_h + (size_t)n * HID);
        for (int k4 = 0; k4 < HID / 4; ++k4) {
            float4 v = rowA[k4];
            float hv4[4] = {v.x, v.y, v.z, v.w};
#pragma unroll
            for (int jj = 0; jj < 4; ++jj) {
                int k = DF + k4 * 4 + jj;
                float hv = hv4[jj];
#pragma unroll
                for (int j = 0; j < 16; ++j) t[j] = fmaf(hv, Wht1[k * HID + f0 + j], t[j]);
            }
        }
#pragma unroll
        for (int j = 0; j < 16; ++j) hh[lane * 65 + f0 + j] = silu_f(t[j]);
    }
    __syncthreads();
    if (n >= N) return;

    int c0 = w * 32;
    float o[32];
#pragma unroll
    for (int j = 0; j < 32; ++j) o[j] = bh2[c0 + j];
    for (int k = 0; k < HID; ++k) {
        float hv = hh[lane * 65 + k];
#pragma unroll
        for (int j = 0; j < 32; ++j) o[j] = fmaf(hv, Wht2[k * DF + c0 + j], o[j]);
    }
    float* oh = out + (size_t)n * DF + c0;
    const float* hrow = h + (size_t)n * DF + c0;
#pragma unroll
    for (int j4 = 0; j4 < 8; ++j4) {
        float4 hv = ((const float4*)hrow)[j4];
        float4 r;
        r.x = hv.x + o[4 * j4];
        r.y = hv.y + o[4 * j4 + 1];
        r.z = hv.z + o[4 * j4 + 2];
        r.w = hv.w + o[4 * j4 + 3];
        ((float4*)oh)[j4] = r;
    }
    if (w == 0) {
        float dv = (float)degI[n];
        float invd = 1.0f / fmaxf(dv, 1.0f);
        float* ox = out + (size_t)N * DF + (size_t)n * 3;
        ox[0] = x[n * 3 + 0] + agg_x[n * 3 + 0] * invd;
        ox[1] = x[n * 3 + 1] + agg_x[n * 3 + 1] * invd;
        ox[2] = x[n * 3 + 2] + agg_x[n * 3 + 2] * invd;
    }
}

extern "C" void kernel_launch(void* const* d_in, const int* in_sizes, int n_in,
                              void* d_out, int out_size, void* d_ws, size_t ws_size,
                              hipStream_t stream) {
    const float* h    = (const float*)d_in[0];
    const float* x    = (const float*)d_in[1];
    const int*   ei   = (const int*)d_in[2];
    const float* We1  = (const float*)d_in[3];
    const float* be1  = (const float*)d_in[4];
    const float* We2  = (const float*)d_in[5];
    const float* be2  = (const float*)d_in[6];
    const float* ln_g = (const float*)d_in[7];
    const float* ln_b = (const float*)d_in[8];
    const float* Wh1  = (const float*)d_in[9];
    const float* bh1  = (const float*)d_in[10];
    const float* Wh2  = (const float*)d_in[11];
    const float* bh2  = (const float*)d_in[12];
    const float* Wx   = (const float*)d_in[13];
    const float* bx   = (const float*)d_in[14];
    const float* Wg   = (const float*)d_in[15];
    const float* bg   = (const float*)d_in[16];

    const int E = in_sizes[2] / 2;
    const int N = in_sizes[0] / DF;
    const int* src = ei;
    const int* dst = ei + E;

    // ---- workspace carve (16B aligned regions) ----
    char* base = (char*)d_ws;
    size_t o = 0;
    auto carve = [&](size_t bytes) -> void* {
        void* r = base + o;
        o = (o + bytes + 15) & ~(size_t)15;
        return r;
    };
    float* agg_h = (float*)carve((size_t)N * HID * 4);
    float* agg_x = (float*)carve((size_t)N * 3 * 4);
    float* Wt1   = (float*)carve(257 * 64 * 4);
    float* Wt2   = (float*)carve(64 * 64 * 4);
    float* Wht1  = (float*)carve(192 * 64 * 4);
    float* Wht2  = (float*)carve(64 * 128 * 4);
    int*   cnt   = (int*)carve((size_t)N * 4);
    int*   off   = (int*)carve(((size_t)N + 1) * 4);
    int*   bsum  = (int*)carve(256 * 4);
    int*   bofs  = (int*)carve(256 * 4);
    int*   dcnt  = (int*)carve(64 * 4);
    int*   dofs  = (int*)carve(64 * 4);
    int*   dnr   = (int*)carve((size_t)N * 4);
    int*   nodeorder = (int*)carve((size_t)N * 4);
    int*   rank  = (int*)carve((size_t)E * 4);
    int*   csr_src = (int*)carve((size_t)E * 4);
    size_t need_full = o;

    // Ps/Pd live in d_out (N*128 <= out_size N*131); d_out is fully
    // overwritten by node_kernel afterwards.
    float* Ps = (float*)d_out;
    float* Pd = Ps + (size_t)N * HID;

    const int gE  = (E + 255) / 256;
    const int Nb  = (N + 1023) / 1024;
    const int gN64 = (N + 63) / 64;

    hipMemsetAsync(cnt, 0, (size_t)N * 4, stream);
    prep_weights<<<(41024 + 255) / 256, 256, 0, stream>>>(We1, We2, Wh1, Wh2,
                                                          Wt1, Wt2, Wht1, Wht2);
    node_pre<<<gN64, 256, 0, stream>>>(h, Wt1, Ps, Pd, N);

    if (ws_size >= need_full) {
        // ---- CSR build ----
        hipMemsetAsync(dcnt, 0, 64 * 4, stream);
        count_kernel<<<gE, 256, 0, stream>>>(dst, cnt, rank, E);
        scan1<<<Nb, 1024, 0, stream>>>(cnt, off, bsum, N);
        scan2<<<1, 64, 0, stream>>>(bsum, bofs, Nb);
        scan3<<<(N + 256) / 256, 256, 0, stream>>>(off, bofs, N, E);
        scatter_src<<<gE, 256, 0, stream>>>(dst, src, rank, off, csr_src, E);
        deghist<<<(N + 255) / 256, 256, 0, stream>>>(cnt, dcnt, dnr, N);
        degscan<<<1, 64, 0, stream>>>(dcnt, dofs);
        degscatter<<<(N + 255) / 256, 256, 0, stream>>>(cnt, dnr, dofs, nodeorder, N);
        // ---- fused gather (no atomics), 8 lanes per node ----
        gather_kernel<<<((size_t)N * GS + 255) / 256, 256, 0, stream>>>(
            csr_src, off, nodeorder, x, Ps, Pd, Wt1, Wt2, be1, be2,
            ln_g, ln_b, Wx, bx, Wg, bg, agg_h, agg_x, N);
    } else {
        // ---- fallback: atomic aggregation ----
        hipMemsetAsync(agg_h, 0, (size_t)N * 67 * 4, stream);
        count_kernel<<<gE, 256, 0, stream>>>(dst, cnt, nullptr, E);
        edge_kernel_atomic<<<gE, 256, 0, stream>>>(src, dst, x, Ps, Pd, Wt1, Wt2,
                                                   be1, be2, ln_g, ln_b, Wx, bx,
                                                   Wg, bg, agg_h, agg_x, E);
    }

    node_kernel<<<gN64, 256, 0, stream>>>(h, x, agg_h, agg_x, cnt,
                                          Wht1, Wht2, bh1, bh2, (float*)d_out, N);
}